// Round 7
// baseline (629.448 us; speedup 1.0000x reference)
//
#include <hip/hip_runtime.h>
#include <hip/hip_bf16.h>

using bf16 = __hip_bfloat16;
typedef __attribute__((ext_vector_type(8))) short short8;    // 8 bf16 = 4 VGPRs (MFMA A/B frag)
typedef __attribute__((ext_vector_type(16))) float f32x16;   // 32x32 MFMA C/D frag

// ---------------------------------------------------------------------------
// All fp32->bf16 casts in ONE launch: blocks [0,8192) = x, [8192,11264) = W.
// ---------------------------------------------------------------------------
__global__ __launch_bounds__(256) void cast_all(const float* __restrict__ x,
                                                const float* __restrict__ Wq,
                                                const float* __restrict__ Wk,
                                                const float* __restrict__ Wv,
                                                bf16* __restrict__ xb, bf16* __restrict__ Wb) {
  const int b = blockIdx.x;
  const float* src;
  bf16* dst;
  if (b < 8192) {
    src = x + (size_t)b * 1024;
    dst = xb + (size_t)b * 1024;
  } else if (b < 9216) {
    src = Wq + (size_t)(b - 8192) * 1024;
    dst = Wb + (size_t)(b - 8192) * 1024;
  } else if (b < 10240) {
    src = Wk + (size_t)(b - 9216) * 1024;
    dst = Wb + (size_t)(b - 8192) * 1024;
  } else {
    src = Wv + (size_t)(b - 10240) * 1024;
    dst = Wb + (size_t)(b - 8192) * 1024;
  }
  const int i = threadIdx.x * 4;
  const float4 f = *(const float4*)(src + i);
  bf16 h[4];
  h[0] = __float2bfloat16(f.x);
  h[1] = __float2bfloat16(f.y);
  h[2] = __float2bfloat16(f.z);
  h[3] = __float2bfloat16(f.w);
  *(uint2*)(dst + i) = *(const uint2*)h;
}

// ---------------------------------------------------------------------------
// R15 = R5 core + cross-tile REGISTER double-buffer of MFMA fragments.
// R1-R6 lesson: every structure serialized {ds_read frags -> lgkm -> MFMA}
// within a wave, so LDS-read time (~512-750 cyc/CU/tile) and MFMA time
// (~516 cyc) ADD -> MfmaUtil plateau 29-37%. This round the frag reads for
// tile kt+1 are issued with NO wait and fly UNDER tile kt's MFMAs.
// Geometry (R5, best-known): block 128(m) x 256(n), 512 thr / 8 waves
// (2m x 4n, wave tile 64x64), BK=32, ring-3 LDS (3 x 24 KB = 72 KiB ->
// 2 blocks/CU), lead-2 staging, counted vmcnt(3) (never 0 in steady loop).
// Steady-state per tile kt:
//   stage(kt+2 -> slot (kt+2)%3)            [3 global_load_lds]
//   s_waitcnt vmcnt(3) lgkmcnt(0)           [kt+1 landed; frags(kt) complete
//                                            -- both free: issued >=1 tile ago]
//   s_barrier                                [after this, slot overwrite-safe
//                                            AND slot kt+1 readable globally]
//   issue 8 ds_read frags(kt+1) -> fOther    [NO wait]
//   setprio(1); 8 MFMA from fCur; setprio(0) [reads fly under MFMAs]
// Overwrite safety: lgkmcnt(0) BEFORE the barrier => no wave passes the
// barrier with in-flight reads of the slot staged right after it.
// Unrolled x2 with named fA/fB (rule #20: no runtime-indexed reg arrays);
// NT is even at all call sites (32, 64). acc lives in AGPRs (R5: VGPR=60);
// frag dbuf adds ~32 VGPR -> fits __launch_bounds__(512,4) = 2 blocks/CU.
// XOR chunk swizzle f(row)=(row+(row>>2))&3, 64 B rows: ~0-conflict (R1/R5).
// ---------------------------------------------------------------------------
template <class Epi>
__device__ __forceinline__ void gemm_nt(const bf16* __restrict__ A, const bf16* __restrict__ B,
                                        int lda, int ldb, int K, int m0, int n0, Epi epi) {
  constexpr int SLOT = 24576;  // A 128x32x2 = 8 KB, B 256x32x2 = 16 KB
  __shared__ char smem[3 * SLOT];
  const int t = threadIdx.x;   // 0..511
  const int lane = t & 63;
  const int wave = t >> 6;     // 0..7
  const int wm = (wave >> 2) * 64;  // m half
  const int wn = (wave & 3) * 64;   // n quarter
  const int rl = lane & 31;
  const int grp = lane >> 5;

  f32x16 acc[2][2];
#pragma unroll
  for (int i = 0; i < 2; ++i)
#pragma unroll
    for (int j = 0; j < 2; ++j)
#pragma unroll
      for (int r = 0; r < 16; ++r) acc[i][j][r] = 0.f;

  // Staging sources. A: 1 instr (512 slots = 128 rows x 4 chunks);
  // B: 2 instrs. slot s holds global chunk (row = s>>2, c = (s&3) ^ f(row)).
  const bf16* gA0;
  {
    const int row = t >> 2;
    const int f = (row + (row >> 2)) & 3;
    gA0 = A + (size_t)(m0 + row) * lda + ((((t & 3) ^ f)) << 3);
  }
  const bf16* gB[2];
#pragma unroll
  for (int j = 0; j < 2; ++j) {
    const int s = j * 512 + t;
    const int row = s >> 2;
    const int f = (row + (row >> 2)) & 3;
    gB[j] = B + (size_t)(n0 + row) * ldb + ((((s & 3) ^ f)) << 3);
  }

  auto stage = [&](int kt, int slot) {
    char* base = smem + slot * SLOT;
    bf16* As = (bf16*)base;
    bf16* Bs = (bf16*)(base + 8192);
    const int k0 = kt * 32;
    __builtin_amdgcn_global_load_lds(
        (const __attribute__((address_space(1))) unsigned int*)(gA0 + k0),
        (__attribute__((address_space(3))) unsigned int*)(As + wave * 512), 16, 0, 0);
#pragma unroll
    for (int j = 0; j < 2; ++j)
      __builtin_amdgcn_global_load_lds(
          (const __attribute__((address_space(1))) unsigned int*)(gB[j] + k0),
          (__attribute__((address_space(3))) unsigned int*)(Bs + (j * 512 + wave * 64) * 8), 16, 0, 0);
  };

  struct Frags {
    short8 af[2][2];  // [ks][mt]
    short8 bv[2][2];  // [ks][nt]
  };
  auto read_frags = [&](int slot, Frags& f) {
    const char* base = smem + slot * SLOT;
    const bf16* As = (const bf16*)base;
    const bf16* Bs = (const bf16*)(base + 8192);
#pragma unroll
    for (int ks = 0; ks < 2; ++ks) {
      const int kb = ks * 2 + grp;  // this lane's 16B k-chunk index
#pragma unroll
      for (int mt = 0; mt < 2; ++mt) {
        const int rowa = wm + mt * 32 + rl;  // 0..127
        const int fa = (rowa + (rowa >> 2)) & 3;
        f.af[ks][mt] = *(const short8*)(As + rowa * 32 + ((kb ^ fa) << 3));
        const int rowb = wn + mt * 32 + rl;  // 0..255
        const int fb = (rowb + (rowb >> 2)) & 3;
        f.bv[ks][mt] = *(const short8*)(Bs + rowb * 32 + ((kb ^ fb) << 3));
      }
    }
  };
  auto mfma_all = [&](const Frags& f) {
    __builtin_amdgcn_s_setprio(1);
#pragma unroll
    for (int ks = 0; ks < 2; ++ks)
#pragma unroll
      for (int mt = 0; mt < 2; ++mt)
#pragma unroll
        for (int nt = 0; nt < 2; ++nt)
          acc[mt][nt] = __builtin_amdgcn_mfma_f32_32x32x16_bf16(f.af[ks][mt], f.bv[ks][nt],
                                                                acc[mt][nt], 0, 0, 0);
    __builtin_amdgcn_s_setprio(0);
  };

  const int NT = K >> 5;  // K-tiles of 32; even (32 or 64) at all call sites

  // Prologue: tiles 0,1 staged; wait tile 0 (tile 1's 3 fly); frags(0) -> fA.
  stage(0, 0);
  stage(1, 1);
  asm volatile("s_waitcnt vmcnt(3)" ::: "memory");
  __builtin_amdgcn_s_barrier();
  __builtin_amdgcn_sched_barrier(0);
  Frags fA, fB;
  read_frags(0, fA);

  int s0 = 0;  // kt % 3 at loop top
  for (int kt = 0; kt < NT; kt += 2) {
    const int s1 = (s0 == 2) ? 0 : s0 + 1;
    const int s2 = (s1 == 2) ? 0 : s1 + 1;
    // ---- even tile kt: compute fA, prefetch frags(kt+1) -> fB ----
    if (kt + 2 < NT) {
      stage(kt + 2, s2);
      asm volatile("s_waitcnt vmcnt(3) lgkmcnt(0)" ::: "memory");
    } else {
      asm volatile("s_waitcnt vmcnt(0) lgkmcnt(0)" ::: "memory");
    }
    __builtin_amdgcn_s_barrier();
    __builtin_amdgcn_sched_barrier(0);
    read_frags(s1, fB);  // no wait: these fly under the MFMAs below
    mfma_all(fA);
    // ---- odd tile kt+1: compute fB, prefetch frags(kt+2) -> fA ----
    if (kt + 3 < NT) {
      stage(kt + 3, s0);
      asm volatile("s_waitcnt vmcnt(3) lgkmcnt(0)" ::: "memory");
    } else {
      asm volatile("s_waitcnt vmcnt(0) lgkmcnt(0)" ::: "memory");
    }
    __builtin_amdgcn_s_barrier();
    __builtin_amdgcn_sched_barrier(0);
    if (kt + 2 < NT) read_frags(s2, fA);
    mfma_all(fB);
    s0 = s2;
  }
  __syncthreads();  // all waves done before epilogue smem reuse

  epi(acc, m0, n0, wm, wn, lane, wave, smem);
}

// C/D row offset within a 32x32 tile for (reg, lane): m74/m101-verified.
__device__ __forceinline__ int c_row(int reg, int lane) {
  return (reg & 3) + 8 * (reg >> 2) + 4 * (lane >> 5);
}

template <class F>
__device__ __forceinline__ void for_each_c(const f32x16 (&acc)[2][2], int wm, int wn, int lane,
                                           F f) {
  const int rl = lane & 31;
#pragma unroll
  for (int mt = 0; mt < 2; ++mt)
#pragma unroll
    for (int nt = 0; nt < 2; ++nt)
#pragma unroll
      for (int reg = 0; reg < 16; ++reg)
        f(wm + mt * 32 + c_row(reg, lane), wn + nt * 32 + rl, acc[mt][nt][reg]);
}

// ---------------------------------------------------------------------------
// Projection: C[8192, 3072] = xb[8192,1024] @ Wb[3072,1024]^T.
// Block 128x256, grid 768 (12 x 64). XCD swizzle: id%8 = XCD owns m-octet
// (g*8 + 0..7), n advancing every 8 slots -> A-octet 2 MB L2-resident.
// n0<1024 -> Q; n0<2048 -> K; else V^T via per-wave LDS transpose.
// ---------------------------------------------------------------------------
__global__ __launch_bounds__(512, 4) void proj_kernel(const bf16* __restrict__ xb,
                                                      const bf16* __restrict__ Wb,
                                                      bf16* __restrict__ Qb,
                                                      bf16* __restrict__ Kb,
                                                      bf16* __restrict__ Vt) {
  const int id = blockIdx.y * 12 + blockIdx.x;  // grid (12, 64)
  const int g = id & 7, s = id >> 3;            // s in [0,96)
  const int m0 = (g * 8 + (s & 7)) * 128;       // 64 m-tiles
  const int n0 = (s >> 3) * 256;                // 12 n-tiles
  gemm_nt(xb, Wb, 1024, 1024, 1024, m0, n0,
          [=](const f32x16 (&acc)[2][2], int m0, int n0, int wm, int wn, int lane, int wave,
              char* smem) {
    if (n0 < 2048) {  // block-uniform branch
      bf16* dst = (n0 < 1024) ? Qb : Kb;
      const int nb = (n0 < 1024) ? n0 : (n0 - 1024);
      for_each_c(acc, wm, wn, lane, [&](int m, int n, float v) {
        dst[(size_t)(m0 + m) * 1024 + nb + n] = __float2bfloat16(v);
      });
    } else {
      // V tile: 2-pass per-wave 32x64 transpose through LDS (reuses staging).
      bf16* T = (bf16*)(smem) + wave * 2304;  // 32 rows x stride 72 = 4608 B/wave
      const int rl = lane & 31;
      const int g4 = 4 * (lane >> 5);
      const int mbase = m0 + wm;
      const int bb = mbase >> 11;
      const int sbase = mbase & 2047;
      const int nvbase = n0 - 2048 + wn;
#pragma unroll
      for (int p = 0; p < 2; ++p) {  // p = nt half (32 n-rows per pass)
#pragma unroll
        for (int mt = 0; mt < 2; ++mt)
#pragma unroll
          for (int q = 0; q < 4; ++q) {
            bf16 h4[4];
#pragma unroll
            for (int r = 0; r < 4; ++r) h4[r] = __float2bfloat16(acc[mt][p][4 * q + r]);
            *(uint2*)(T + rl * 72 + mt * 32 + 8 * q + g4) = *(const uint2*)h4;
          }
        asm volatile("s_waitcnt lgkmcnt(0)" ::: "memory");  // wave-local LDS RAW
#pragma unroll
        for (int i = 0; i < 4; ++i) {
          const int nl = i * 8 + (lane >> 3);
          const int ml = (lane & 7) * 8;
          const short8 val = *(const short8*)(T + nl * 72 + ml);
          *(short8*)(Vt + ((size_t)bb * 1024 + nvbase + p * 32 + nl) * 2048 + sbase + ml) = val;
        }
        asm volatile("s_waitcnt lgkmcnt(0)" ::: "memory");  // reads retired before reuse
      }
    }
  });
}

// ---------------------------------------------------------------------------
// QK^T + fused exp: E[z][m][n] = exp(Q.K/32) bf16 + per-256-col-tile partial
// row sums Lpart[z][8][2048]. No max-subtract (s ~ N(0,1); exp safe in fp32).
// Block 128x256, grid (128, 4) = exactly 2 blocks/CU. Per z, XCD g owns a
// 4m x 4n patch of 256-tiles (A 2 MB + B 2 MB in its private L2).
// ---------------------------------------------------------------------------
__global__ __launch_bounds__(512, 4) void qk_exp_kernel(const bf16* __restrict__ Qb,
                                                        const bf16* __restrict__ Kb,
                                                        bf16* __restrict__ E,
                                                        float* __restrict__ Lpart) {
  const int z = blockIdx.y;
  const int id2 = blockIdx.x;              // [0,128)
  const int g = id2 & 7, s = id2 >> 3;     // s in [0,16)
  const int m0 = ((g & 3) * 4 + (s & 3)) * 128;   // 16 m-tiles
  const int n0 = ((g >> 2) * 4 + (s >> 2)) * 256; // 8 n-tiles
  const bf16* A = Qb + (size_t)z * 2048 * 1024;
  const bf16* B = Kb + (size_t)z * 2048 * 1024;
  bf16* Ez = E + (size_t)z * 2048 * 2048;
  float* Lz = Lpart + (size_t)z * 8 * 2048;
  gemm_nt(A, B, 1024, 1024, 1024, m0, n0,
          [=](const f32x16 (&acc)[2][2], int m0, int n0, int wm, int wn, int lane, int wave,
              char* smem) {
    float* Lp = (float*)smem;  // [128][4] partial sums (wn quarters)
    const int rl = lane & 31;
#pragma unroll
    for (int mt = 0; mt < 2; ++mt)
#pragma unroll
      for (int reg = 0; reg < 16; ++reg) {
        const int mr = wm + mt * 32 + c_row(reg, lane);
        float s2 = 0.f;
#pragma unroll
        for (int nt = 0; nt < 2; ++nt) {
          const float e = __expf(acc[mt][nt][reg] * 0.03125f);
          Ez[(size_t)(m0 + mr) * 2048 + n0 + wn + nt * 32 + rl] = __float2bfloat16(e);
          s2 += e;
        }
        // sum over the 32 rl-lanes (same row within each half-wave group)
        s2 += __shfl_xor(s2, 1, 64);
        s2 += __shfl_xor(s2, 2, 64);
        s2 += __shfl_xor(s2, 4, 64);
        s2 += __shfl_xor(s2, 8, 64);
        s2 += __shfl_xor(s2, 16, 64);
        if (rl == 0) Lp[mr * 4 + (wave & 3)] = s2;
      }
    __syncthreads();
    const int t = threadIdx.x;
    if (t < 128)
      Lz[(n0 >> 8) * 2048 + m0 + t] =
          Lp[t * 4 + 0] + Lp[t * 4 + 1] + Lp[t * 4 + 2] + Lp[t * 4 + 3];
  });
}

// ---------------------------------------------------------------------------
// out[z][q][d] = invL[z][q] * sum_k E[z][q,k] * Vt[z][d,k].  K = 2048.
// Block 128x256, grid (64, 4) = 256 blocks (1/CU). invL from Lpart.
// ---------------------------------------------------------------------------
__global__ __launch_bounds__(512, 4) void pv_kernel(const bf16* __restrict__ E,
                                                    const bf16* __restrict__ Vt,
                                                    const float* __restrict__ Lpart,
                                                    float* __restrict__ out) {
  const int z = blockIdx.y;
  const int id2 = blockIdx.x;              // [0,64)
  const int g = id2 & 7, s = id2 >> 3;     // s in [0,8)
  const int m0 = ((g & 3) * 4 + (s & 3)) * 128;   // 16 m-tiles
  const int n0 = ((g >> 2) * 2 + (s >> 2)) * 256; // 4 n-tiles
  const bf16* A = E + (size_t)z * 2048 * 2048;
  const bf16* B = Vt + (size_t)z * 1024 * 2048;
  const float* Lz = Lpart + (size_t)z * 8 * 2048;
  float* oz = out + (size_t)z * 2048 * 1024;
  gemm_nt(A, B, 2048, 2048, 2048, m0, n0,
          [=](const f32x16 (&acc)[2][2], int m0, int n0, int wm, int wn, int lane, int wave,
              char* smem) {
    float* Lsm = (float*)smem;  // invL for this block's 128 rows
    const int t = threadIdx.x;
    if (t < 128) {
      float s2 = 0.f;
#pragma unroll
      for (int i = 0; i < 8; ++i) s2 += Lz[(size_t)i * 2048 + m0 + t];
      Lsm[t] = 1.f / s2;
    }
    __syncthreads();
    const int rl = lane & 31;
#pragma unroll
    for (int mt = 0; mt < 2; ++mt)
#pragma unroll
      for (int reg = 0; reg < 16; ++reg) {
        const int ml = wm + mt * 32 + c_row(reg, lane);
        const float il = Lsm[ml];
#pragma unroll
        for (int nt = 0; nt < 2; ++nt)
          oz[(size_t)(m0 + ml) * 1024 + n0 + wn + nt * 32 + rl] = acc[mt][nt][reg] * il;
      }
  });
}

// ---------------------------------------------------------------------------
extern "C" void kernel_launch(void* const* d_in, const int* in_sizes, int n_in,
                              void* d_out, int out_size, void* d_ws, size_t ws_size,
                              hipStream_t stream) {
  const float* x = (const float*)d_in[0];
  const float* Wq = (const float*)d_in[1];
  const float* Wk = (const float*)d_in[2];
  const float* Wv = (const float*)d_in[3];
  float* out = (float*)d_out;

  // Workspace layout (~102 MB)
  char* w = (char*)d_ws;
  bf16* xb = (bf16*)w; w += (size_t)8192 * 1024 * 2;
  bf16* Wb = (bf16*)w; w += (size_t)3072 * 1024 * 2;
  bf16* Qb = (bf16*)w; w += (size_t)8192 * 1024 * 2;
  bf16* Kb = (bf16*)w; w += (size_t)8192 * 1024 * 2;
  bf16* Vt = (bf16*)w; w += (size_t)8192 * 1024 * 2;
  bf16* E  = (bf16*)w; w += (size_t)4 * 2048 * 2048 * 2;
  float* Lpart = (float*)w; w += (size_t)4 * 8 * 2048 * 4;

  // All casts in one launch
  cast_all<<<11264, 256, 0, stream>>>(x, Wq, Wk, Wv, xb, Wb);

  // Fused QKV projection (Q,K row-major bf16; V transposed bf16)
  proj_kernel<<<dim3(12, 64), 512, 0, stream>>>(xb, Wb, Qb, Kb, Vt);

  // Scores -> exp (no max-subtract) + partial row sums per 256-col tile
  qk_exp_kernel<<<dim3(128, 4), 512, 0, stream>>>(Qb, Kb, E, Lpart);

  // Attention output with fused 1/L normalization
  pv_kernel<<<dim3(64, 4), 512, 0, stream>>>(E, Vt, Lpart, out);
}

// Round 8
// 235.719 us; speedup vs baseline: 2.6703x; 2.6703x over previous
//
#include <hip/hip_runtime.h>
#include <hip/hip_bf16.h>

using bf16 = __hip_bfloat16;
typedef __attribute__((ext_vector_type(8))) short short8;    // 8 bf16 = 4 VGPRs (MFMA A/B frag)
typedef __attribute__((ext_vector_type(16))) float f32x16;   // 32x32 MFMA C/D frag

// ---------------------------------------------------------------------------
// All fp32->bf16 casts: 4 rows per block (region boundaries are 4-row
// aligned: 8192/9216/10240). 4 float4 per thread. Grid 2816.
// ---------------------------------------------------------------------------
__global__ __launch_bounds__(256) void cast_all(const float* __restrict__ x,
                                                const float* __restrict__ Wq,
                                                const float* __restrict__ Wk,
                                                const float* __restrict__ Wv,
                                                bf16* __restrict__ xb, bf16* __restrict__ Wb) {
  const int r0 = blockIdx.x << 2;  // first row of 4
  const float* src;
  bf16* dst;
  if (r0 < 8192) {
    src = x + (size_t)r0 * 1024;
    dst = xb + (size_t)r0 * 1024;
  } else if (r0 < 9216) {
    src = Wq + (size_t)(r0 - 8192) * 1024;
    dst = Wb + (size_t)(r0 - 8192) * 1024;
  } else if (r0 < 10240) {
    src = Wk + (size_t)(r0 - 9216) * 1024;
    dst = Wb + (size_t)(r0 - 8192) * 1024;
  } else {
    src = Wv + (size_t)(r0 - 10240) * 1024;
    dst = Wb + (size_t)(r0 - 8192) * 1024;
  }
  const int i = threadIdx.x * 16;
#pragma unroll
  for (int q = 0; q < 4; ++q) {
    const float4 f = *(const float4*)(src + i + q * 4);
    bf16 h[4];
    h[0] = __float2bfloat16(f.x);
    h[1] = __float2bfloat16(f.y);
    h[2] = __float2bfloat16(f.z);
    h[3] = __float2bfloat16(f.w);
    *(uint2*)(dst + i + q * 4) = *(const uint2*)h;
  }
}

// ---------------------------------------------------------------------------
// R16: R5 core UNCHANGED (proven 229 us; proj ~845 TF ~= 93% of the
// m97-structure ceiling, LDS-port-bound), templated on BN so pv can run a
// 256-thr 128x128 variant at 3 blocks/CU (R5's pv was 1 blk/CU, 2 w/SIMD).
// R7 lesson (scratch blowup): frag locals must never be address-taken —
// "memory"-clobber asm forces address-taken locals to spill every tile.
// Core (per tile kt): 8 ds_read frags -> stage(kt+2, lead-2 ring-3) ->
// lgkm(0) -> setprio 8 MFMA -> vmcnt(L)[counted, never 0 steady] -> barrier.
// BN=256: 512 thr, 8 waves (2m x 4n), slot 24 KB, L=3, 2 blk/CU.
// BN=128: 256 thr, 4 waves (2m x 2n), slot 16 KB, L=4, 3 blk/CU.
// XOR chunk swizzle f(row)=(row+(row>>2))&3, 64 B rows: ~0 conflicts.
// ---------------------------------------------------------------------------
template <int BN, class Epi>
__device__ __forceinline__ void gemm_nt(const bf16* __restrict__ A, const bf16* __restrict__ B,
                                        int lda, int ldb, int K, int m0, int n0, Epi epi) {
  constexpr int THREADS = BN * 2;           // 512 or 256
  constexpr int NA = 8192 / (THREADS * 16); // A gll instrs: 1 or 2
  constexpr int NB = (BN * 64) / (THREADS * 16);  // B gll instrs: 2
  constexpr int L = NA + NB;                // loads per tile: 3 or 4
  constexpr int SLOT = (128 + BN) * 64;     // bytes: 24576 or 16384
  __shared__ char smem[3 * SLOT];
  const int t = threadIdx.x;
  const int lane = t & 63;
  const int wave = t >> 6;
  const int wm = (BN == 256) ? (wave >> 2) * 64 : (wave >> 1) * 64;
  const int wn = (BN == 256) ? (wave & 3) * 64 : (wave & 1) * 64;
  const int rl = lane & 31;
  const int grp = lane >> 5;

  f32x16 acc[2][2];
#pragma unroll
  for (int i = 0; i < 2; ++i)
#pragma unroll
    for (int j = 0; j < 2; ++j)
#pragma unroll
      for (int r = 0; r < 16; ++r) acc[i][j][r] = 0.f;

  // Staging sources: slot s holds global chunk (row = s>>2, c=(s&3)^f(row)).
  const bf16* gA[NA];
#pragma unroll
  for (int j = 0; j < NA; ++j) {
    const int s = j * THREADS + t;
    const int row = s >> 2;
    const int f = (row + (row >> 2)) & 3;
    gA[j] = A + (size_t)(m0 + row) * lda + ((((s & 3) ^ f)) << 3);
  }
  const bf16* gB[NB];
#pragma unroll
  for (int j = 0; j < NB; ++j) {
    const int s = j * THREADS + t;
    const int row = s >> 2;
    const int f = (row + (row >> 2)) & 3;
    gB[j] = B + (size_t)(n0 + row) * ldb + ((((s & 3) ^ f)) << 3);
  }

  auto stage = [&](int kt, int slot) {
    char* base = smem + slot * SLOT;
    bf16* As = (bf16*)base;
    bf16* Bs = (bf16*)(base + 8192);
    const int k0 = kt * 32;
#pragma unroll
    for (int j = 0; j < NA; ++j)
      __builtin_amdgcn_global_load_lds(
          (const __attribute__((address_space(1))) unsigned int*)(gA[j] + k0),
          (__attribute__((address_space(3))) unsigned int*)(As + (j * THREADS + wave * 64) * 8),
          16, 0, 0);
#pragma unroll
    for (int j = 0; j < NB; ++j)
      __builtin_amdgcn_global_load_lds(
          (const __attribute__((address_space(1))) unsigned int*)(gB[j] + k0),
          (__attribute__((address_space(3))) unsigned int*)(Bs + (j * THREADS + wave * 64) * 8),
          16, 0, 0);
  };

  const int NT = K >> 5;  // K-tiles of 32

  // Prologue: tiles 0,1 staged; wait tile 0 only (tile 1's L stay in flight).
  stage(0, 0);
  stage(1, 1);
  if constexpr (BN == 256) {
    asm volatile("s_waitcnt vmcnt(3)" ::: "memory");
  } else {
    asm volatile("s_waitcnt vmcnt(4)" ::: "memory");
  }
  __builtin_amdgcn_s_barrier();
  __builtin_amdgcn_sched_barrier(0);

  int s0 = 0;  // kt % 3
  for (int kt = 0; kt < NT; ++kt) {
    const int s1 = (s0 == 2) ? 0 : s0 + 1;
    const int s2 = (s1 == 2) ? 0 : s1 + 1;
    const char* base = smem + s0 * SLOT;
    const bf16* As = (const bf16*)base;
    const bf16* Bs = (const bf16*)(base + 8192);

    if (kt + 2 < NT) stage(kt + 2, s2);  // lead-2: waited ~1.5 tiles from now

    short8 af[2][2], bv[2][2];  // [ks][mt] — plain locals, never address-taken
#pragma unroll
    for (int ks = 0; ks < 2; ++ks) {
      const int kb = ks * 2 + grp;  // this lane's 16B k-chunk index
#pragma unroll
      for (int mt = 0; mt < 2; ++mt) {
        const int rowa = wm + mt * 32 + rl;
        const int fa = (rowa + (rowa >> 2)) & 3;
        af[ks][mt] = *(const short8*)(As + rowa * 32 + ((kb ^ fa) << 3));
        const int rowb = wn + mt * 32 + rl;
        const int fb = (rowb + (rowb >> 2)) & 3;
        bv[ks][mt] = *(const short8*)(Bs + rowb * 32 + ((kb ^ fb) << 3));
      }
    }
    __builtin_amdgcn_sched_barrier(0);
    asm volatile("s_waitcnt lgkmcnt(0)" ::: "memory");
    __builtin_amdgcn_sched_barrier(0);
    __builtin_amdgcn_s_setprio(1);
#pragma unroll
    for (int ks = 0; ks < 2; ++ks)
#pragma unroll
      for (int mt = 0; mt < 2; ++mt)
#pragma unroll
        for (int nt = 0; nt < 2; ++nt)
          acc[mt][nt] = __builtin_amdgcn_mfma_f32_32x32x16_bf16(af[ks][mt], bv[ks][nt],
                                                                acc[mt][nt], 0, 0, 0);
    __builtin_amdgcn_s_setprio(0);
    __builtin_amdgcn_sched_barrier(0);
    if (kt + 1 < NT) {
      if (kt + 2 < NT) {
        if constexpr (BN == 256) {
          asm volatile("s_waitcnt vmcnt(3)" ::: "memory");  // kt+1 landed; kt+2 flies
        } else {
          asm volatile("s_waitcnt vmcnt(4)" ::: "memory");
        }
      } else {
        asm volatile("s_waitcnt vmcnt(0)" ::: "memory");  // once, at kt == NT-2
      }
      __builtin_amdgcn_s_barrier();
      __builtin_amdgcn_sched_barrier(0);
    }
    s0 = s1;
  }
  __syncthreads();  // all waves done before epilogue smem reuse

  epi(acc, m0, n0, wm, wn, lane, wave, smem);
}

// C/D row offset within a 32x32 tile for (reg, lane): m74/m101-verified.
__device__ __forceinline__ int c_row(int reg, int lane) {
  return (reg & 3) + 8 * (reg >> 2) + 4 * (lane >> 5);
}

template <class F>
__device__ __forceinline__ void for_each_c(const f32x16 (&acc)[2][2], int wm, int wn, int lane,
                                           F f) {
  const int rl = lane & 31;
#pragma unroll
  for (int mt = 0; mt < 2; ++mt)
#pragma unroll
    for (int nt = 0; nt < 2; ++nt)
#pragma unroll
      for (int reg = 0; reg < 16; ++reg)
        f(wm + mt * 32 + c_row(reg, lane), wn + nt * 32 + rl, acc[mt][nt][reg]);
}

// ---------------------------------------------------------------------------
// Projection: C[8192, 3072] = xb[8192,1024] @ Wb[3072,1024]^T.
// Block 128x256, grid 768 (12 x 64), 2 blk/CU. XCD swizzle: id%8 = XCD owns
// m-octet, n advancing every 8 slots -> A-octet 2 MB L2-resident.
// n0<1024 -> Q; n0<2048 -> K; else V^T via per-wave LDS transpose.
// ---------------------------------------------------------------------------
__global__ __launch_bounds__(512, 4) void proj_kernel(const bf16* __restrict__ xb,
                                                      const bf16* __restrict__ Wb,
                                                      bf16* __restrict__ Qb,
                                                      bf16* __restrict__ Kb,
                                                      bf16* __restrict__ Vt) {
  const int id = blockIdx.y * 12 + blockIdx.x;  // grid (12, 64)
  const int g = id & 7, s = id >> 3;            // s in [0,96)
  const int m0 = (g * 8 + (s & 7)) * 128;       // 64 m-tiles
  const int n0 = (s >> 3) * 256;                // 12 n-tiles
  gemm_nt<256>(xb, Wb, 1024, 1024, 1024, m0, n0,
          [=](const f32x16 (&acc)[2][2], int m0, int n0, int wm, int wn, int lane, int wave,
              char* smem) {
    if (n0 < 2048) {  // block-uniform branch
      bf16* dst = (n0 < 1024) ? Qb : Kb;
      const int nb = (n0 < 1024) ? n0 : (n0 - 1024);
      for_each_c(acc, wm, wn, lane, [&](int m, int n, float v) {
        dst[(size_t)(m0 + m) * 1024 + nb + n] = __float2bfloat16(v);
      });
    } else {
      // V tile: 2-pass per-wave 32x64 transpose through LDS (reuses staging).
      bf16* T = (bf16*)(smem) + wave * 2304;  // 32 rows x stride 72 = 4608 B/wave
      const int rl = lane & 31;
      const int g4 = 4 * (lane >> 5);
      const int mbase = m0 + wm;
      const int bb = mbase >> 11;
      const int sbase = mbase & 2047;
      const int nvbase = n0 - 2048 + wn;
#pragma unroll
      for (int p = 0; p < 2; ++p) {  // p = nt half (32 n-rows per pass)
#pragma unroll
        for (int mt = 0; mt < 2; ++mt)
#pragma unroll
          for (int q = 0; q < 4; ++q) {
            bf16 h4[4];
#pragma unroll
            for (int r = 0; r < 4; ++r) h4[r] = __float2bfloat16(acc[mt][p][4 * q + r]);
            *(uint2*)(T + rl * 72 + mt * 32 + 8 * q + g4) = *(const uint2*)h4;
          }
        asm volatile("s_waitcnt lgkmcnt(0)" ::: "memory");  // wave-local LDS RAW
#pragma unroll
        for (int i = 0; i < 4; ++i) {
          const int nl = i * 8 + (lane >> 3);
          const int ml = (lane & 7) * 8;
          const short8 val = *(const short8*)(T + nl * 72 + ml);
          *(short8*)(Vt + ((size_t)bb * 1024 + nvbase + p * 32 + nl) * 2048 + sbase + ml) = val;
        }
        asm volatile("s_waitcnt lgkmcnt(0)" ::: "memory");  // reads retired before reuse
      }
    }
  });
}

// ---------------------------------------------------------------------------
// QK^T + fused exp: E[z][m][n] = exp(Q.K/32) bf16 + per-256-col-tile partial
// row sums Lpart[z][8][2048]. No max-subtract (s ~ N(0,1); exp safe in fp32).
// Block 128x256, grid (128, 4) = exactly 2 blocks/CU. Per z, XCD g owns a
// 4m x 4n patch of 256-tiles (A 2 MB + B 2 MB in its private L2).
// ---------------------------------------------------------------------------
__global__ __launch_bounds__(512, 4) void qk_exp_kernel(const bf16* __restrict__ Qb,
                                                        const bf16* __restrict__ Kb,
                                                        bf16* __restrict__ E,
                                                        float* __restrict__ Lpart) {
  const int z = blockIdx.y;
  const int id2 = blockIdx.x;              // [0,128)
  const int g = id2 & 7, s = id2 >> 3;     // s in [0,16)
  const int m0 = ((g & 3) * 4 + (s & 3)) * 128;   // 16 m-tiles
  const int n0 = ((g >> 2) * 4 + (s >> 2)) * 256; // 8 n-tiles
  const bf16* A = Qb + (size_t)z * 2048 * 1024;
  const bf16* B = Kb + (size_t)z * 2048 * 1024;
  bf16* Ez = E + (size_t)z * 2048 * 2048;
  float* Lz = Lpart + (size_t)z * 8 * 2048;
  gemm_nt<256>(A, B, 1024, 1024, 1024, m0, n0,
          [=](const f32x16 (&acc)[2][2], int m0, int n0, int wm, int wn, int lane, int wave,
              char* smem) {
    float* Lp = (float*)smem;  // [128][4] partial sums (wn quarters)
    const int rl = lane & 31;
#pragma unroll
    for (int mt = 0; mt < 2; ++mt)
#pragma unroll
      for (int reg = 0; reg < 16; ++reg) {
        const int mr = wm + mt * 32 + c_row(reg, lane);
        float s2 = 0.f;
#pragma unroll
        for (int nt = 0; nt < 2; ++nt) {
          const float e = __expf(acc[mt][nt][reg] * 0.03125f);
          Ez[(size_t)(m0 + mr) * 2048 + n0 + wn + nt * 32 + rl] = __float2bfloat16(e);
          s2 += e;
        }
        // sum over the 32 rl-lanes (same row within each half-wave group)
        s2 += __shfl_xor(s2, 1, 64);
        s2 += __shfl_xor(s2, 2, 64);
        s2 += __shfl_xor(s2, 4, 64);
        s2 += __shfl_xor(s2, 8, 64);
        s2 += __shfl_xor(s2, 16, 64);
        if (rl == 0) Lp[mr * 4 + (wave & 3)] = s2;
      }
    __syncthreads();
    const int t = threadIdx.x;
    if (t < 128)
      Lz[(n0 >> 8) * 2048 + m0 + t] =
          Lp[t * 4 + 0] + Lp[t * 4 + 1] + Lp[t * 4 + 2] + Lp[t * 4 + 3];
  });
}

// ---------------------------------------------------------------------------
// out[z][q][d] = invL[z][q] * sum_k E[z][q,k] * Vt[z][d,k].  K = 2048.
// R16: 256-thr 128x128 blocks, grid (128,4) = 512 blocks = 2/CU minimum
// (ring 48 KB -> 3 blk/CU capacity). R5 ran pv at 1 blk/CU, 2 waves/SIMD.
// Per z, XCD g owns a 4m x 4n patch. invL from Lpart block-cooperatively.
// ---------------------------------------------------------------------------
__global__ __launch_bounds__(256, 4) void pv_kernel(const bf16* __restrict__ E,
                                                    const bf16* __restrict__ Vt,
                                                    const float* __restrict__ Lpart,
                                                    float* __restrict__ out) {
  const int z = blockIdx.y;
  const int id2 = blockIdx.x;              // [0,128)
  const int g = id2 & 7, s = id2 >> 3;     // s in [0,16)
  const int m0 = ((g & 3) * 4 + (s & 3)) * 128;   // 16 m-tiles
  const int n0 = ((g >> 2) * 4 + (s >> 2)) * 128; // 8 n-tiles
  const bf16* A = E + (size_t)z * 2048 * 2048;
  const bf16* B = Vt + (size_t)z * 1024 * 2048;
  const float* Lz = Lpart + (size_t)z * 8 * 2048;
  float* oz = out + (size_t)z * 2048 * 1024;
  gemm_nt<128>(A, B, 2048, 2048, 2048, m0, n0,
          [=](const f32x16 (&acc)[2][2], int m0, int n0, int wm, int wn, int lane, int wave,
              char* smem) {
    float* Lsm = (float*)smem;  // invL for this block's 128 rows
    const int t = threadIdx.x;
    if (t < 128) {
      float s2 = 0.f;
#pragma unroll
      for (int i = 0; i < 8; ++i) s2 += Lz[(size_t)i * 2048 + m0 + t];
      Lsm[t] = 1.f / s2;
    }
    __syncthreads();
    const int rl = lane & 31;
#pragma unroll
    for (int mt = 0; mt < 2; ++mt)
#pragma unroll
      for (int reg = 0; reg < 16; ++reg) {
        const int ml = wm + mt * 32 + c_row(reg, lane);
        const float il = Lsm[ml];
#pragma unroll
        for (int nt = 0; nt < 2; ++nt)
          oz[(size_t)(m0 + ml) * 1024 + n0 + wn + nt * 32 + rl] = acc[mt][nt][reg] * il;
      }
  });
}

// ---------------------------------------------------------------------------
extern "C" void kernel_launch(void* const* d_in, const int* in_sizes, int n_in,
                              void* d_out, int out_size, void* d_ws, size_t ws_size,
                              hipStream_t stream) {
  const float* x = (const float*)d_in[0];
  const float* Wq = (const float*)d_in[1];
  const float* Wk = (const float*)d_in[2];
  const float* Wv = (const float*)d_in[3];
  float* out = (float*)d_out;

  // Workspace layout (~102 MB)
  char* w = (char*)d_ws;
  bf16* xb = (bf16*)w; w += (size_t)8192 * 1024 * 2;
  bf16* Wb = (bf16*)w; w += (size_t)3072 * 1024 * 2;
  bf16* Qb = (bf16*)w; w += (size_t)8192 * 1024 * 2;
  bf16* Kb = (bf16*)w; w += (size_t)8192 * 1024 * 2;
  bf16* Vt = (bf16*)w; w += (size_t)8192 * 1024 * 2;
  bf16* E  = (bf16*)w; w += (size_t)4 * 2048 * 2048 * 2;
  float* Lpart = (float*)w; w += (size_t)4 * 8 * 2048 * 4;

  // All casts in one launch
  cast_all<<<2816, 256, 0, stream>>>(x, Wq, Wk, Wv, xb, Wb);

  // Fused QKV projection (Q,K row-major bf16; V transposed bf16)
  proj_kernel<<<dim3(12, 64), 512, 0, stream>>>(xb, Wb, Qb, Kb, Vt);

  // Scores -> exp (no max-subtract) + partial row sums per 256-col tile
  qk_exp_kernel<<<dim3(128, 4), 512, 0, stream>>>(Qb, Kb, E, Lpart);

  // Attention output with fused 1/L normalization
  pv_kernel<<<dim3(128, 4), 256, 0, stream>>>(E, Vt, Lpart, out);
}

// Round 9
// 229.175 us; speedup vs baseline: 2.7466x; 1.0286x over previous
//
#include <hip/hip_runtime.h>
#include <hip/hip_bf16.h>

using bf16 = __hip_bfloat16;
typedef __attribute__((ext_vector_type(8))) short short8;    // 8 bf16 = 4 VGPRs (MFMA A/B frag)
typedef __attribute__((ext_vector_type(16))) float f32x16;   // 32x32 MFMA C/D frag

// ---------------------------------------------------------------------------
// All fp32->bf16 casts in ONE launch: blocks [0,8192) = x, [8192,11264) = W.
// (R5 config restored — R8's 4-row variant was part of a +6 us regression.)
// ---------------------------------------------------------------------------
__global__ __launch_bounds__(256) void cast_all(const float* __restrict__ x,
                                                const float* __restrict__ Wq,
                                                const float* __restrict__ Wk,
                                                const float* __restrict__ Wv,
                                                bf16* __restrict__ xb, bf16* __restrict__ Wb) {
  const int b = blockIdx.x;
  const float* src;
  bf16* dst;
  if (b < 8192) {
    src = x + (size_t)b * 1024;
    dst = xb + (size_t)b * 1024;
  } else if (b < 9216) {
    src = Wq + (size_t)(b - 8192) * 1024;
    dst = Wb + (size_t)(b - 8192) * 1024;
  } else if (b < 10240) {
    src = Wk + (size_t)(b - 9216) * 1024;
    dst = Wb + (size_t)(b - 8192) * 1024;
  } else {
    src = Wv + (size_t)(b - 10240) * 1024;
    dst = Wb + (size_t)(b - 8192) * 1024;
  }
  const int i = threadIdx.x * 4;
  const float4 f = *(const float4*)(src + i);
  bf16 h[4];
  h[0] = __float2bfloat16(f.x);
  h[1] = __float2bfloat16(f.y);
  h[2] = __float2bfloat16(f.z);
  h[3] = __float2bfloat16(f.w);
  *(uint2*)(dst + i) = *(const uint2*)h;
}

// ---------------------------------------------------------------------------
// R17 = R5 geometry (block 128x256, 512 thr / 8 waves 2m x 4n, wave 64x64,
// BK=32, ring-3 LDS 72 KiB -> 2 blk/CU, lead-2 staging, counted vmcnt) with
// ONE core change: NO forced lgkmcnt(0)/sched_barrier before the MFMAs.
// R8 diagnosis: 8 ds_read_b128 (~96 cyc LDS port) and 8 MFMA (~64 cyc) were
// SERIALIZED by my own pre-MFMA drain -> MfmaUtil pinned at 36% = 64/(96+64+ovh).
// The compiler, left alone, emits counted lgkmcnt(6/4/...) between ds_reads
// and dependent MFMAs (m97 asm evidence), so the first MFMA issues after ~2
// reads and the remaining reads fly under MFMAs.
// Safety without the drain:
//  - ring overwrite: combined "vmcnt(N) lgkmcnt(0)" AFTER the MFMAs, before
//    s_barrier (free in steady state — MFMAs already consumed every read) =>
//    no wave passes the barrier with reads of the next stage target in flight.
//  - read hoisting: sched_barrier(0) kept immediately after each s_barrier.
//  - no inline-asm ds_reads => all read->MFMA deps compiler-visible (rule #18
//    inapplicable); frag locals plain (never address-taken — R7 lesson).
// ---------------------------------------------------------------------------
template <int BN, class Epi>
__device__ __forceinline__ void gemm_nt(const bf16* __restrict__ A, const bf16* __restrict__ B,
                                        int lda, int ldb, int K, int m0, int n0, Epi epi) {
  constexpr int THREADS = BN * 2;           // 512
  constexpr int NA = 8192 / (THREADS * 16); // A gll instrs per tile
  constexpr int NB = (BN * 64) / (THREADS * 16);  // B gll instrs per tile
  constexpr int L = NA + NB;                // loads per tile
  constexpr int SLOT = (128 + BN) * 64;     // bytes per ring slot
  __shared__ char smem[3 * SLOT];
  const int t = threadIdx.x;
  const int lane = t & 63;
  const int wave = t >> 6;
  const int wm = (BN == 256) ? (wave >> 2) * 64 : (wave >> 1) * 64;
  const int wn = (BN == 256) ? (wave & 3) * 64 : (wave & 1) * 64;
  const int rl = lane & 31;
  const int grp = lane >> 5;

  f32x16 acc[2][2];
#pragma unroll
  for (int i = 0; i < 2; ++i)
#pragma unroll
    for (int j = 0; j < 2; ++j)
#pragma unroll
      for (int r = 0; r < 16; ++r) acc[i][j][r] = 0.f;

  // Staging sources: slot s holds global chunk (row = s>>2, c=(s&3)^f(row)),
  // XOR chunk swizzle f(row)=(row+(row>>2))&3; 64 B rows (~0 conflicts, R1/R5).
  const bf16* gA[NA];
#pragma unroll
  for (int j = 0; j < NA; ++j) {
    const int s = j * THREADS + t;
    const int row = s >> 2;
    const int f = (row + (row >> 2)) & 3;
    gA[j] = A + (size_t)(m0 + row) * lda + ((((s & 3) ^ f)) << 3);
  }
  const bf16* gB[NB];
#pragma unroll
  for (int j = 0; j < NB; ++j) {
    const int s = j * THREADS + t;
    const int row = s >> 2;
    const int f = (row + (row >> 2)) & 3;
    gB[j] = B + (size_t)(n0 + row) * ldb + ((((s & 3) ^ f)) << 3);
  }

  auto stage = [&](int kt, int slot) {
    char* base = smem + slot * SLOT;
    bf16* As = (bf16*)base;
    bf16* Bs = (bf16*)(base + 8192);
    const int k0 = kt * 32;
#pragma unroll
    for (int j = 0; j < NA; ++j)
      __builtin_amdgcn_global_load_lds(
          (const __attribute__((address_space(1))) unsigned int*)(gA[j] + k0),
          (__attribute__((address_space(3))) unsigned int*)(As + (j * THREADS + wave * 64) * 8),
          16, 0, 0);
#pragma unroll
    for (int j = 0; j < NB; ++j)
      __builtin_amdgcn_global_load_lds(
          (const __attribute__((address_space(1))) unsigned int*)(gB[j] + k0),
          (__attribute__((address_space(3))) unsigned int*)(Bs + (j * THREADS + wave * 64) * 8),
          16, 0, 0);
  };

  const int NT = K >> 5;  // K-tiles of 32

  // Prologue: tiles 0,1 staged; wait tile 0 only (tile 1's L stay in flight).
  stage(0, 0);
  stage(1, 1);
  if constexpr (L == 3) {
    asm volatile("s_waitcnt vmcnt(3)" ::: "memory");
  } else {
    asm volatile("s_waitcnt vmcnt(4)" ::: "memory");
  }
  __builtin_amdgcn_s_barrier();
  __builtin_amdgcn_sched_barrier(0);

  int s0 = 0;  // kt % 3
  for (int kt = 0; kt < NT; ++kt) {
    const int s1 = (s0 == 2) ? 0 : s0 + 1;
    const int s2 = (s1 == 2) ? 0 : s1 + 1;
    const char* base = smem + s0 * SLOT;
    const bf16* As = (const bf16*)base;
    const bf16* Bs = (const bf16*)(base + 8192);

    if (kt + 2 < NT) stage(kt + 2, s2);  // lead-2: waited ~1.5 tiles from now

    short8 af[2][2], bv[2][2];  // plain locals, never address-taken (R7)
#pragma unroll
    for (int ks = 0; ks < 2; ++ks) {
      const int kb = ks * 2 + grp;  // this lane's 16B k-chunk index
#pragma unroll
      for (int mt = 0; mt < 2; ++mt) {
        const int rowa = wm + mt * 32 + rl;
        const int fa = (rowa + (rowa >> 2)) & 3;
        af[ks][mt] = *(const short8*)(As + rowa * 32 + ((kb ^ fa) << 3));
        const int rowb = wn + mt * 32 + rl;
        const int fb = (rowb + (rowb >> 2)) & 3;
        bv[ks][mt] = *(const short8*)(Bs + rowb * 32 + ((kb ^ fb) << 3));
      }
    }
    // NO forced wait here (R17): compiler inserts counted lgkmcnt between
    // each ds_read and its first dependent MFMA -> reads overlap MFMAs.
    __builtin_amdgcn_s_setprio(1);
#pragma unroll
    for (int ks = 0; ks < 2; ++ks)
#pragma unroll
      for (int mt = 0; mt < 2; ++mt)
#pragma unroll
        for (int nt = 0; nt < 2; ++nt)
          acc[mt][nt] = __builtin_amdgcn_mfma_f32_32x32x16_bf16(af[ks][mt], bv[ks][nt],
                                                                acc[mt][nt], 0, 0, 0);
    __builtin_amdgcn_s_setprio(0);
    if (kt + 1 < NT) {
      // Combined drain: own kt+1 staging landed (counted — kt+2's L fly on),
      // and all own ds_reads retired (free: MFMAs consumed them) so the slot
      // staged right after the barrier is overwrite-safe for everyone.
      if (kt + 2 < NT) {
        if constexpr (L == 3) {
          asm volatile("s_waitcnt vmcnt(3) lgkmcnt(0)" ::: "memory");
        } else {
          asm volatile("s_waitcnt vmcnt(4) lgkmcnt(0)" ::: "memory");
        }
      } else {
        asm volatile("s_waitcnt vmcnt(0) lgkmcnt(0)" ::: "memory");  // kt == NT-2
      }
      __builtin_amdgcn_s_barrier();
      __builtin_amdgcn_sched_barrier(0);  // no next-tile ds_read hoists above
    }
    s0 = s1;
  }
  __syncthreads();  // all waves done before epilogue smem reuse

  epi(acc, m0, n0, wm, wn, lane, wave, smem);
}

// C/D row offset within a 32x32 tile for (reg, lane): m74/m101-verified.
__device__ __forceinline__ int c_row(int reg, int lane) {
  return (reg & 3) + 8 * (reg >> 2) + 4 * (lane >> 5);
}

template <class F>
__device__ __forceinline__ void for_each_c(const f32x16 (&acc)[2][2], int wm, int wn, int lane,
                                           F f) {
  const int rl = lane & 31;
#pragma unroll
  for (int mt = 0; mt < 2; ++mt)
#pragma unroll
    for (int nt = 0; nt < 2; ++nt)
#pragma unroll
      for (int reg = 0; reg < 16; ++reg)
        f(wm + mt * 32 + c_row(reg, lane), wn + nt * 32 + rl, acc[mt][nt][reg]);
}

// ---------------------------------------------------------------------------
// Projection: C[8192, 3072] = xb[8192,1024] @ Wb[3072,1024]^T.
// Block 128x256, grid 768 (12 x 64), 2 blk/CU. XCD swizzle: id%8 = XCD owns
// m-octet, n advancing every 8 slots -> A-octet 2 MB L2-resident.
// n0<1024 -> Q; n0<2048 -> K; else V^T via per-wave LDS transpose.
// ---------------------------------------------------------------------------
__global__ __launch_bounds__(512, 4) void proj_kernel(const bf16* __restrict__ xb,
                                                      const bf16* __restrict__ Wb,
                                                      bf16* __restrict__ Qb,
                                                      bf16* __restrict__ Kb,
                                                      bf16* __restrict__ Vt) {
  const int id = blockIdx.y * 12 + blockIdx.x;  // grid (12, 64)
  const int g = id & 7, s = id >> 3;            // s in [0,96)
  const int m0 = (g * 8 + (s & 7)) * 128;       // 64 m-tiles
  const int n0 = (s >> 3) * 256;                // 12 n-tiles
  gemm_nt<256>(xb, Wb, 1024, 1024, 1024, m0, n0,
          [=](const f32x16 (&acc)[2][2], int m0, int n0, int wm, int wn, int lane, int wave,
              char* smem) {
    if (n0 < 2048) {  // block-uniform branch
      bf16* dst = (n0 < 1024) ? Qb : Kb;
      const int nb = (n0 < 1024) ? n0 : (n0 - 1024);
      for_each_c(acc, wm, wn, lane, [&](int m, int n, float v) {
        dst[(size_t)(m0 + m) * 1024 + nb + n] = __float2bfloat16(v);
      });
    } else {
      // V tile: 2-pass per-wave 32x64 transpose through LDS (reuses staging).
      bf16* T = (bf16*)(smem) + wave * 2304;  // 32 rows x stride 72 = 4608 B/wave
      const int rl = lane & 31;
      const int g4 = 4 * (lane >> 5);
      const int mbase = m0 + wm;
      const int bb = mbase >> 11;
      const int sbase = mbase & 2047;
      const int nvbase = n0 - 2048 + wn;
#pragma unroll
      for (int p = 0; p < 2; ++p) {  // p = nt half (32 n-rows per pass)
#pragma unroll
        for (int mt = 0; mt < 2; ++mt)
#pragma unroll
          for (int q = 0; q < 4; ++q) {
            bf16 h4[4];
#pragma unroll
            for (int r = 0; r < 4; ++r) h4[r] = __float2bfloat16(acc[mt][p][4 * q + r]);
            *(uint2*)(T + rl * 72 + mt * 32 + 8 * q + g4) = *(const uint2*)h4;
          }
        asm volatile("s_waitcnt lgkmcnt(0)" ::: "memory");  // wave-local LDS RAW
#pragma unroll
        for (int i = 0; i < 4; ++i) {
          const int nl = i * 8 + (lane >> 3);
          const int ml = (lane & 7) * 8;
          const short8 val = *(const short8*)(T + nl * 72 + ml);
          *(short8*)(Vt + ((size_t)bb * 1024 + nvbase + p * 32 + nl) * 2048 + sbase + ml) = val;
        }
        asm volatile("s_waitcnt lgkmcnt(0)" ::: "memory");  // reads retired before reuse
      }
    }
  });
}

// ---------------------------------------------------------------------------
// QK^T + fused exp: E[z][m][n] = exp(Q.K/32) bf16 + per-256-col-tile partial
// row sums Lpart[z][8][2048]. No max-subtract (s ~ N(0,1); exp safe in fp32).
// Block 128x256, grid (128, 4) = exactly 2 blocks/CU. Per z, XCD g owns a
// 4m x 4n patch of 256-tiles (A 2 MB + B 2 MB in its private L2).
// ---------------------------------------------------------------------------
__global__ __launch_bounds__(512, 4) void qk_exp_kernel(const bf16* __restrict__ Qb,
                                                        const bf16* __restrict__ Kb,
                                                        bf16* __restrict__ E,
                                                        float* __restrict__ Lpart) {
  const int z = blockIdx.y;
  const int id2 = blockIdx.x;              // [0,128)
  const int g = id2 & 7, s = id2 >> 3;     // s in [0,16)
  const int m0 = ((g & 3) * 4 + (s & 3)) * 128;   // 16 m-tiles
  const int n0 = ((g >> 2) * 4 + (s >> 2)) * 256; // 8 n-tiles
  const bf16* A = Qb + (size_t)z * 2048 * 1024;
  const bf16* B = Kb + (size_t)z * 2048 * 1024;
  bf16* Ez = E + (size_t)z * 2048 * 2048;
  float* Lz = Lpart + (size_t)z * 8 * 2048;
  gemm_nt<256>(A, B, 1024, 1024, 1024, m0, n0,
          [=](const f32x16 (&acc)[2][2], int m0, int n0, int wm, int wn, int lane, int wave,
              char* smem) {
    float* Lp = (float*)smem;  // [128][4] partial sums (wn quarters)
    const int rl = lane & 31;
#pragma unroll
    for (int mt = 0; mt < 2; ++mt)
#pragma unroll
      for (int reg = 0; reg < 16; ++reg) {
        const int mr = wm + mt * 32 + c_row(reg, lane);
        float s2 = 0.f;
#pragma unroll
        for (int nt = 0; nt < 2; ++nt) {
          const float e = __expf(acc[mt][nt][reg] * 0.03125f);
          Ez[(size_t)(m0 + mr) * 2048 + n0 + wn + nt * 32 + rl] = __float2bfloat16(e);
          s2 += e;
        }
        // sum over the 32 rl-lanes (same row within each half-wave group)
        s2 += __shfl_xor(s2, 1, 64);
        s2 += __shfl_xor(s2, 2, 64);
        s2 += __shfl_xor(s2, 4, 64);
        s2 += __shfl_xor(s2, 8, 64);
        s2 += __shfl_xor(s2, 16, 64);
        if (rl == 0) Lp[mr * 4 + (wave & 3)] = s2;
      }
    __syncthreads();
    const int t = threadIdx.x;
    if (t < 128)
      Lz[(n0 >> 8) * 2048 + m0 + t] =
          Lp[t * 4 + 0] + Lp[t * 4 + 1] + Lp[t * 4 + 2] + Lp[t * 4 + 3];
  });
}

// ---------------------------------------------------------------------------
// out[z][q][d] = invL[z][q] * sum_k E[z][q,k] * Vt[z][d,k].  K = 2048.
// R5 config restored: block 128x256, grid (64, 4). invL from Lpart.
// ---------------------------------------------------------------------------
__global__ __launch_bounds__(512, 4) void pv_kernel(const bf16* __restrict__ E,
                                                    const bf16* __restrict__ Vt,
                                                    const float* __restrict__ Lpart,
                                                    float* __restrict__ out) {
  const int z = blockIdx.y;
  const int id2 = blockIdx.x;              // [0,64)
  const int g = id2 & 7, s = id2 >> 3;     // s in [0,8)
  const int m0 = ((g & 3) * 4 + (s & 3)) * 128;   // 16 m-tiles
  const int n0 = ((g >> 2) * 2 + (s >> 2)) * 256; // 4 n-tiles
  const bf16* A = E + (size_t)z * 2048 * 2048;
  const bf16* B = Vt + (size_t)z * 1024 * 2048;
  const float* Lz = Lpart + (size_t)z * 8 * 2048;
  float* oz = out + (size_t)z * 2048 * 1024;
  gemm_nt<256>(A, B, 2048, 2048, 2048, m0, n0,
          [=](const f32x16 (&acc)[2][2], int m0, int n0, int wm, int wn, int lane, int wave,
              char* smem) {
    float* Lsm = (float*)smem;  // invL for this block's 128 rows
    const int t = threadIdx.x;
    if (t < 128) {
      float s2 = 0.f;
#pragma unroll
      for (int i = 0; i < 8; ++i) s2 += Lz[(size_t)i * 2048 + m0 + t];
      Lsm[t] = 1.f / s2;
    }
    __syncthreads();
    const int rl = lane & 31;
#pragma unroll
    for (int mt = 0; mt < 2; ++mt)
#pragma unroll
      for (int reg = 0; reg < 16; ++reg) {
        const int ml = wm + mt * 32 + c_row(reg, lane);
        const float il = Lsm[ml];
#pragma unroll
        for (int nt = 0; nt < 2; ++nt)
          oz[(size_t)(m0 + ml) * 1024 + n0 + wn + nt * 32 + rl] = acc[mt][nt][reg] * il;
      }
  });
}

// ---------------------------------------------------------------------------
extern "C" void kernel_launch(void* const* d_in, const int* in_sizes, int n_in,
                              void* d_out, int out_size, void* d_ws, size_t ws_size,
                              hipStream_t stream) {
  const float* x = (const float*)d_in[0];
  const float* Wq = (const float*)d_in[1];
  const float* Wk = (const float*)d_in[2];
  const float* Wv = (const float*)d_in[3];
  float* out = (float*)d_out;

  // Workspace layout (~102 MB)
  char* w = (char*)d_ws;
  bf16* xb = (bf16*)w; w += (size_t)8192 * 1024 * 2;
  bf16* Wb = (bf16*)w; w += (size_t)3072 * 1024 * 2;
  bf16* Qb = (bf16*)w; w += (size_t)8192 * 1024 * 2;
  bf16* Kb = (bf16*)w; w += (size_t)8192 * 1024 * 2;
  bf16* Vt = (bf16*)w; w += (size_t)8192 * 1024 * 2;
  bf16* E  = (bf16*)w; w += (size_t)4 * 2048 * 2048 * 2;
  float* Lpart = (float*)w; w += (size_t)4 * 8 * 2048 * 4;

  // All casts in one launch
  cast_all<<<11264, 256, 0, stream>>>(x, Wq, Wk, Wv, xb, Wb);

  // Fused QKV projection (Q,K row-major bf16; V transposed bf16)
  proj_kernel<<<dim3(12, 64), 512, 0, stream>>>(xb, Wb, Qb, Kb, Vt);

  // Scores -> exp (no max-subtract) + partial row sums per 256-col tile
  qk_exp_kernel<<<dim3(128, 4), 512, 0, stream>>>(Qb, Kb, E, Lpart);

  // Attention output with fused 1/L normalization
  pv_kernel<<<dim3(64, 4), 512, 0, stream>>>(E, Vt, Lpart, out);
}